// Round 14
// baseline (870.792 us; speedup 1.0000x reference)
//
#include <hip/hip_runtime.h>
#include <cstdint>
#include <cstddef>

// ---------------- types / helpers ----------------
typedef __bf16 bf16x8 __attribute__((ext_vector_type(8)));
typedef unsigned short u16x8 __attribute__((ext_vector_type(8)));
typedef float  f32x4  __attribute__((ext_vector_type(4)));
typedef unsigned short u16;

#define GLDS16(GP, LP) __builtin_amdgcn_global_load_lds( \
    (const __attribute__((address_space(1))) void*)(GP), \
    (__attribute__((address_space(3))) void*)(LP), 16, 0, 0)

__device__ __forceinline__ float b2f(u16 u) {
  unsigned int x = ((unsigned int)u) << 16;
  return __builtin_bit_cast(float, x);
}
__device__ __forceinline__ u16 f2b(float f) {  // RNE
  unsigned int u = __builtin_bit_cast(unsigned int, f);
  unsigned int r = (u + 0x7fffu + ((u >> 16) & 1u)) >> 16;
  return (u16)r;
}

// ---------------- problem constants ----------------
constexpr int Bc  = 2;
constexpr int Sc  = 2048;
constexpr int Hc  = 3584;
constexpr int NHc = 16;
constexpr int HDc = 256;
constexpr int NKV = 8;
constexpr int QD  = NHc * HDc;   // 4096
constexpr int QS  = 8192;        // fused QKV row stride (4096 Q + 2048 K + 2048 V)
constexpr float SCALE   = 0.0625f;   // 256^-0.5
constexpr float CAP     = 50.0f;
constexpr float INV_CAP = 1.0f / 50.0f;

// capped = CAP * tanh(raw*SCALE/CAP) = CAP - 2*CAP/(1 + exp(2*raw*SCALE/CAP))
// branch-free, graceful at +-inf, 1 transcendental.
__device__ __forceinline__ float softcap(float raw) {
  float e = __expf(raw * (2.0f * SCALE * INV_CAP));
  return CAP - (2.0f * CAP) * __builtin_amdgcn_rcpf(1.0f + e);
}

// ---------------- rope table ----------------
__global__ void rope_table_k(float* __restrict__ cosT, float* __restrict__ sinT) {
  int idx = blockIdx.x * 256 + threadIdx.x;      // 2048*128 total
  int s = idx >> 7, i = idx & 127;
  float inv = expf((float)i * -0.0719557841560639f);
  float ang = (float)s * inv;
  cosT[idx] = cosf(ang);
  sinT[idx] = sinf(ang);
}

// ---------------- fp32 -> bf16 elementwise (vectorized) ----------------
__global__ void cvt_f32_bf16(const float4* __restrict__ in, ushort4* __restrict__ out, int n4) {
  int i = blockIdx.x * 256 + threadIdx.x;
  int st = gridDim.x * 256;
  for (; i < n4; i += st) {
    float4 v = in[i];
    ushort4 u;
    u.x = f2b(v.x); u.y = f2b(v.y); u.z = f2b(v.z); u.w = f2b(v.w);
    out[i] = u;
  }
}

// ---------------- fp32 [R][C] -> bf16 [C][R] transpose-convert ----------------
__global__ void transpose_cvt(const float* __restrict__ in, u16* __restrict__ out, int R, int C) {
  __shared__ float t[32][33];
  int c0 = blockIdx.x * 32, r0 = blockIdx.y * 32;
  int tx = threadIdx.x, ty = threadIdx.y;   // (32,8)
#pragma unroll
  for (int i = 0; i < 4; i++)
    t[ty + i * 8][tx] = in[(size_t)(r0 + ty + i * 8) * C + c0 + tx];
  __syncthreads();
#pragma unroll
  for (int i = 0; i < 4; i++)
    out[(size_t)(c0 + ty + i * 8) * R + r0 + tx] = f2b(t[tx][ty + i * 8]);
}

// ---------------- bf16 per-head V transpose: QKV[.][6144+...] -> [B][NKV][256][S] ----------------
__global__ void transpose_v(const u16* __restrict__ QKV, u16* __restrict__ Vt) {
  __shared__ u16 t[32][33];
  int b = blockIdx.z >> 3, kvh = blockIdx.z & 7;
  int s0 = blockIdx.x * 32, d0 = blockIdx.y * 32;
  int tx = threadIdx.x, ty = threadIdx.y;
#pragma unroll
  for (int i = 0; i < 4; i++)
    t[ty + i * 8][tx] = QKV[(size_t)(b * Sc + s0 + ty + i * 8) * QS + 6144 + kvh * HDc + d0 + tx];
  __syncthreads();
#pragma unroll
  for (int i = 0; i < 4; i++)
    Vt[(size_t)((b * NKV + kvh) * HDc + d0 + ty + i * 8) * Sc + s0 + tx] = t[tx][ty + i * 8];
}

// ---------------- RoPE in-place on bf16, row stride QS (K only; Q fused in attn) ----------------
template <int NH>
__global__ void rope_apply(u16* __restrict__ X, const float* __restrict__ cosT,
                           const float* __restrict__ sinT) {
  constexpr int LS = (NH == 16) ? 4 : 3;
  int idx = blockIdx.x * 256 + threadIdx.x;
  const int i4 = (idx & 31) << 2;
  const int h = (idx >> 5) & (NH - 1);
  const int row = idx >> (5 + LS);
  const int s = row & (Sc - 1);
  u16* p = X + (size_t)row * QS + h * 256 + i4;
  ushort4 lo = *(const ushort4*)p;
  ushort4 hi = *(const ushort4*)(p + 128);
  float4 c = *(const float4*)(cosT + s * 128 + i4);
  float4 sn = *(const float4*)(sinT + s * 128 + i4);
  ushort4 nlo, nhi;
  { float xl = b2f(lo.x), xh = b2f(hi.x);
    nlo.x = f2b(xl * c.x - xh * sn.x); nhi.x = f2b(xh * c.x + xl * sn.x); }
  { float xl = b2f(lo.y), xh = b2f(hi.y);
    nlo.y = f2b(xl * c.y - xh * sn.y); nhi.y = f2b(xh * c.y + xl * sn.y); }
  { float xl = b2f(lo.z), xh = b2f(hi.z);
    nlo.z = f2b(xl * c.z - xh * sn.z); nhi.z = f2b(xh * c.z + xl * sn.z); }
  { float xl = b2f(lo.w), xh = b2f(hi.w);
    nlo.w = f2b(xl * c.w - xh * sn.w); nhi.w = f2b(xh * c.w + xl * sn.w); }
  *(ushort4*)p = nlo;
  *(ushort4*)(p + 128) = nhi;
}

// ---------------- GEMM 256x256 (Round-6 variant, best measured) ----------------
// 8 waves (2M x 4N), wave tile 128x64, BK=64, double-buffered LDS (128 KiB).
// All 24 ds_read_b128/K-tile issued fence-free up front; ONE sync point per K-tile.
// slot^(row&7) swizzle (0 conflicts), setprio (T5), XCD+GROUP_M=8 map (T1/L2).
template <typename OT>
__global__ __launch_bounds__(512, 1) void gemm256(const u16* __restrict__ A,
                                                  const u16* __restrict__ Bt,
                                                  OT* __restrict__ C,
                                                  int M, int N, int K, int GM) {
  __shared__ alignas(16) u16 As[2][256 * 64];   // 32 KiB each
  __shared__ alignas(16) u16 Bs[2][256 * 64];
  const int nwg = gridDim.x;
  const int cpx = nwg >> 3;                      // nwg % 8 == 0
  const int wgid = (blockIdx.x & 7) * cpx + (blockIdx.x >> 3);
  const int GN = nwg / GM;
  const int width = 8 * GN;
  const int grp = wgid / width;
  const int rem = wgid - grp * width;
  const int m0 = (grp * 8 + (rem & 7)) * 256;
  const int n0 = (rem >> 3) * 256;
  const int tid = threadIdx.x;
  const int lane = tid & 63;
  const int w = tid >> 6;
  const int wm = w >> 2, wn = w & 3;
  const int lg = lane >> 4, lr = lane & 15;
  const int nkt = K >> 6;

  auto STAGE = [&](int buf, int kt) {
    const int k0 = kt * 64;
#pragma unroll
    for (int i = 0; i < 4; i++) {
      int c = i * 512 + tid;
      int row = c >> 3, slot = c & 7;
      GLDS16(A + (size_t)(m0 + row) * K + k0 + (slot ^ (row & 7)) * 8,
             (char*)As[buf] + c * 16);
    }
#pragma unroll
    for (int i = 0; i < 4; i++) {
      int c = i * 512 + tid;
      int row = c >> 3, slot = c & 7;
      GLDS16(Bt + (size_t)(n0 + row) * K + k0 + (slot ^ (row & 7)) * 8,
             (char*)Bs[buf] + c * 16);
    }
  };

  f32x4 acc[8][4] = {};

  STAGE(0, 0);
  STAGE(1, 1);
  asm volatile("s_waitcnt vmcnt(8)" ::: "memory");   // tile 0 landed, tile 1 in flight
  __builtin_amdgcn_sched_barrier(0);
  __builtin_amdgcn_s_barrier();

  for (int kt = 0; kt < nkt; ++kt) {
    const int buf = kt & 1;
    bf16x8 bfr[4][2], af[4][2], af2[4][2];
#pragma unroll
    for (int j = 0; j < 4; j++)
#pragma unroll
      for (int ks = 0; ks < 2; ks++) {
        int row = wn * 64 + j * 16 + lr;
        bfr[j][ks] = *(const bf16x8*)&Bs[buf][row * 64 + ((ks * 4 + lg) ^ (row & 7)) * 8];
      }
#pragma unroll
    for (int i = 0; i < 4; i++)
#pragma unroll
      for (int ks = 0; ks < 2; ks++) {
        int row = wm * 128 + i * 16 + lr;
        af[i][ks] = *(const bf16x8*)&As[buf][row * 64 + ((ks * 4 + lg) ^ (row & 7)) * 8];
      }
#pragma unroll
    for (int i = 0; i < 4; i++)
#pragma unroll
      for (int ks = 0; ks < 2; ks++) {
        int row = wm * 128 + 64 + i * 16 + lr;
        af2[i][ks] = *(const bf16x8*)&As[buf][row * 64 + ((ks * 4 + lg) ^ (row & 7)) * 8];
      }
    __builtin_amdgcn_s_setprio(1);
#pragma unroll
    for (int i = 0; i < 4; i++)
#pragma unroll
      for (int j = 0; j < 4; j++)
#pragma unroll
        for (int ks = 0; ks < 2; ks++)
          acc[i][j] = __builtin_amdgcn_mfma_f32_16x16x32_bf16(
              af[i][ks], bfr[j][ks], acc[i][j], 0, 0, 0);
    __builtin_amdgcn_s_setprio(0);
    asm volatile("s_waitcnt vmcnt(0) lgkmcnt(0)" ::: "memory");
    __builtin_amdgcn_sched_barrier(0);
    __builtin_amdgcn_s_barrier();
    if (kt + 2 < nkt) STAGE(buf, kt + 2);
    __builtin_amdgcn_s_setprio(1);
#pragma unroll
    for (int i = 0; i < 4; i++)
#pragma unroll
      for (int j = 0; j < 4; j++)
#pragma unroll
        for (int ks = 0; ks < 2; ks++)
          acc[4 + i][j] = __builtin_amdgcn_mfma_f32_16x16x32_bf16(
              af2[i][ks], bfr[j][ks], acc[4 + i][j], 0, 0, 0);
    __builtin_amdgcn_s_setprio(0);
  }

#pragma unroll
  for (int i = 0; i < 8; i++) {
    const int row = m0 + wm * 128 + i * 16 + lg * 4;
#pragma unroll
    for (int j = 0; j < 4; j++) {
      const int col = n0 + wn * 64 + j * 16 + lr;
#pragma unroll
      for (int r = 0; r < 4; r++) {
        if constexpr (sizeof(OT) == 2)
          C[(size_t)(row + r) * N + col] = f2b(acc[i][j][r]);
        else
          C[(size_t)(row + r) * N + col] = acc[i][j][r];
      }
    }
  }
}

// ---------------- flash attention (R13 structure, V read from L2 instead of LDS) ----------------
// grid (16,16,2); qt = bz ? 15-bx : bx (balanced pairing). 8 waves x 16 q-rows.
// K tile 64 DOUBLE-buffered in LDS (64 KB) + Ps col-XOR (16 KB) = 80 KB.
// V is NOT LDS-staged (catalog #7): each (b,kvh) V^T slice is 1 MB -> L2-resident
// and reused by 32 blocks; vf fragments are 16B-contiguous along t in Vtr, read
// directly from global (4 lg-chunks form a 64B line per d-row). This halves
// LDS reads/tile (66->34), halves STAGE (vmcnt(8)->vmcnt(4)), moves V to the
// vector-mem pipe (parallel to LDS), and cuts LDS to 80 KB.
// Q-RoPE fused in prolog (pairs (d,d+128) are same-lane: qf[kk] <-> qf[kk+4]).
__global__ __launch_bounds__(512) void attn_fwd(const u16* __restrict__ QKV,
                                                const u16* __restrict__ Vt,
                                                const float* __restrict__ cosT,
                                                const float* __restrict__ sinT,
                                                u16* __restrict__ AO) {
  constexpr int KVB = 64;
  __shared__ alignas(16) u16 Ks[2][KVB * 256];   // [t][d], swizzled, 32 KB each
  __shared__ alignas(16) u16 Ps[8][16][64];      // per-wave P, col ^= (q&7)<<3
  const int bx = blockIdx.x, h = blockIdx.y, b = blockIdx.z;
  const int qt = b ? (15 - bx) : bx;
  const int q0 = qt * 128;
  const int kvh = h >> 1;
  const int tid = threadIdx.x, w = tid >> 6, lane = tid & 63;
  const int lg = lane >> 4, lr = lane & 15;
  const int myrow = q0 + w * 16 + lr;            // this lane's Q row (A-operand row)

  // Q fragments + fused RoPE. qf[kk] covers d = kk*32 + lg*8 + e (kk<4 lo, kk>=4 hi).
  u16x8 qr[8];
  {
    const u16* qp = QKV + (size_t)(b * Sc + myrow) * QS + h * HDc + lg * 8;
#pragma unroll
    for (int kk = 0; kk < 8; kk++) qr[kk] = *(const u16x8*)(qp + kk * 32);
    const float* ct = cosT + myrow * 128 + lg * 8;
    const float* st = sinT + myrow * 128 + lg * 8;
#pragma unroll
    for (int kk = 0; kk < 4; kk++)
#pragma unroll
      for (int q4 = 0; q4 < 2; q4++) {
        float4 c = *(const float4*)(ct + kk * 32 + q4 * 4);
        float4 s = *(const float4*)(st + kk * 32 + q4 * 4);
#pragma unroll
        for (int e = 0; e < 4; e++) {
          int ei = q4 * 4 + e;
          float cc = (&c.x)[e], ss = (&s.x)[e];
          float lo = b2f(qr[kk][ei]), hi = b2f(qr[kk + 4][ei]);
          qr[kk][ei]     = f2b(lo * cc - hi * ss);
          qr[kk + 4][ei] = f2b(hi * cc + lo * ss);
        }
      }
  }
  bf16x8 qf[8];
#pragma unroll
  for (int kk = 0; kk < 8; kk++) qf[kk] = __builtin_bit_cast(bf16x8, qr[kk]);

  f32x4 o[16] = {};
  float m_r[4], l_r[4];
#pragma unroll
  for (int r = 0; r < 4; r++) { m_r[r] = -1e30f; l_r[r] = 0.0f; }
  const int my_qrow = q0 + w * 16 + lg * 4;
  const int wave_min_row = q0 + w * 16;
  const int wave_max_row = q0 + w * 16 + 15;

  const u16* kbase = QKV + (size_t)(b * Sc) * QS + 4096 + kvh * HDc;
  const u16* vbase = Vt + (size_t)((b * NKV + kvh) * HDc) * Sc;

  auto STAGE = [&](int buf, int t0) {
    // K tile [64][256]: 2048 16B-chunks, source pre-swizzled (slot ^ (row&7))
#pragma unroll
    for (int i = 0; i < 4; i++) {
      int c = i * 512 + tid;
      int row = c >> 5, slot = c & 31;
      GLDS16(kbase + (size_t)(t0 + row) * QS + (slot ^ (row & 7)) * 8,
             (char*)Ks[buf] + c * 16);
    }
  };

  const int nt = 2 * qt + 2;   // 64-wide tiles, t0 = 0 .. q0+64
  int cur = 0;
  STAGE(0, 0);
  for (int ti = 0; ti < nt; ++ti) {
    const int t0 = ti * 64;
    if (ti + 1 < nt) {
      STAGE(cur ^ 1, t0 + 64);
      asm volatile("s_waitcnt vmcnt(4)" ::: "memory");   // tile-ti K landed; next in flight
    } else {
      asm volatile("s_waitcnt vmcnt(0)" ::: "memory");
    }
    __builtin_amdgcn_sched_barrier(0);
    __builtin_amdgcn_s_barrier();

    if (t0 <= wave_max_row) {   // wave-uniform: skip fully-masked tiles
      const u16* KsT = Ks[cur];

      // scores: 4 t-frags x 8 k-steps (swizzled reads)
      f32x4 sc[4];
#pragma unroll
      for (int j = 0; j < 4; j++) {
        f32x4 a = {0.f, 0.f, 0.f, 0.f};
        const int row = j * 16 + lr;
#pragma unroll
        for (int kk = 0; kk < 8; kk++) {
          int s0 = (kk * 4 + lg) ^ (lr & 7);
          bf16x8 kf = *(const bf16x8*)&KsT[row * 256 + s0 * 8];
          a = __builtin_amdgcn_mfma_f32_16x16x32_bf16(qf[kk], kf, a, 0, 0, 0);
        }
        sc[j] = a;
      }

      float tmax[4] = {-1e30f, -1e30f, -1e30f, -1e30f};
      if (t0 + 63 > wave_min_row) {  // tile touches diagonal for this wave
#pragma unroll
        for (int j = 0; j < 4; j++)
#pragma unroll
          for (int r = 0; r < 4; r++) {
            float x = softcap(sc[j][r]);
            if (t0 + j * 16 + lr > my_qrow + r) x = -1e9f;
            sc[j][r] = x;
            tmax[r] = fmaxf(tmax[r], x);
          }
      } else {
#pragma unroll
        for (int j = 0; j < 4; j++)
#pragma unroll
          for (int r = 0; r < 4; r++) {
            float x = softcap(sc[j][r]);
            sc[j][r] = x;
            tmax[r] = fmaxf(tmax[r], x);
          }
      }
#pragma unroll
      for (int xm = 1; xm < 16; xm <<= 1)
#pragma unroll
        for (int r = 0; r < 4; r++) tmax[r] = fmaxf(tmax[r], __shfl_xor(tmax[r], xm, 64));

      // T13 defer-max
      bool need = false;
#pragma unroll
      for (int r = 0; r < 4; r++) need |= (tmax[r] > m_r[r] + 8.0f);
      if (__any(need)) {
        float scal[4];
#pragma unroll
        for (int r = 0; r < 4; r++) {
          float mn = fmaxf(m_r[r], tmax[r]);
          scal[r] = __expf(m_r[r] - mn);
          m_r[r] = mn;
          l_r[r] *= scal[r];
        }
#pragma unroll
        for (int df = 0; df < 16; df++)
#pragma unroll
          for (int r = 0; r < 4; r++) o[df][r] *= scal[r];
      }

      float psum[4] = {0.f, 0.f, 0.f, 0.f};
#pragma unroll
      for (int j = 0; j < 4; j++)
#pragma unroll
        for (int r = 0; r < 4; r++) {
          float p = __expf(sc[j][r] - m_r[r]);
          psum[r] += p;
          // col-XOR swizzle: element (q, t) stored at col t ^ ((q&7)<<3)
          int q = lg * 4 + r;
          Ps[w][q][(j * 16 + lr) ^ ((q & 7) << 3)] = f2b(p);
        }
#pragma unroll
      for (int xm = 1; xm < 16; xm <<= 1)
#pragma unroll
        for (int r = 0; r < 4; r++) psum[r] += __shfl_xor(psum[r], xm, 64);
#pragma unroll
      for (int r = 0; r < 4; r++) l_r[r] += psum[r];

      // PV: A = P rows (q=lr) from LDS, B = V^T rows (d) DIRECT FROM GLOBAL (L2).
      // vf addresses are softmax-independent -> compiler hoists loads over the
      // softmax chain; 4 lg-chunks per d-row form one 64B L2 line.
      bf16x8 pf0 = *(const bf16x8*)&Ps[w][lr][(lg ^ (lr & 7)) * 8];
      bf16x8 pf1 = *(const bf16x8*)&Ps[w][lr][((lg ^ 4) ^ (lr & 7)) * 8];
#pragma unroll
      for (int df = 0; df < 16; df++) {
        const int d = df * 16 + lr;
        const u16* vrow = vbase + (size_t)d * Sc + t0;
        bf16x8 vf0 = *(const bf16x8*)(vrow + lg * 8);
        o[df] = __builtin_amdgcn_mfma_f32_16x16x32_bf16(pf0, vf0, o[df], 0, 0, 0);
        bf16x8 vf1 = *(const bf16x8*)(vrow + 32 + lg * 8);
        o[df] = __builtin_amdgcn_mfma_f32_16x16x32_bf16(pf1, vf1, o[df], 0, 0, 0);
      }
    }

    __builtin_amdgcn_s_barrier();
    cur ^= 1;
  }

  float inv_l[4];
#pragma unroll
  for (int r = 0; r < 4; r++) inv_l[r] = 1.0f / l_r[r];
  u16* op = AO + (size_t)(b * Sc + my_qrow) * QD + h * HDc + lr;
#pragma unroll
  for (int df = 0; df < 16; df++)
#pragma unroll
    for (int r = 0; r < 4; r++)
      op[(size_t)r * QD + df * 16] = f2b(o[df][r] * inv_l[r]);
}

// ---------------- host launcher ----------------
extern "C" void kernel_launch(void* const* d_in, const int* in_sizes, int n_in,
                              void* d_out, int out_size, void* d_ws, size_t ws_size,
                              hipStream_t stream) {
  (void)in_sizes; (void)n_in; (void)out_size; (void)ws_size;
  const float* hs = (const float*)d_in[0];
  // d_in[1] = attention_mask (causal; applied analytically)
  const float* Wq = (const float*)d_in[2];
  const float* Wk = (const float*)d_in[3];
  const float* Wv = (const float*)d_in[4];
  const float* Wo = (const float*)d_in[5];
  float* out = (float*)d_out;
  char* ws = (char*)d_ws;

  float* cosT = (float*)(ws + 0);                 // 1 MB
  float* sinT = (float*)(ws + 1048576);           // 1 MB
  u16* hsb    = (u16*)(ws + 2097152);             // [4096][3584]
  u16* Wqkvt  = (u16*)(ws + 31457280);            // [8192][3584]
  u16* Wot    = (u16*)(ws + 90177536);            // [3584][4096]
  u16* QKVb   = (u16*)(ws + 119537664);           // [4096][8192]
  u16* Vtr    = hsb;     // alias: hsb dead after QKV GEMM
  u16* AO     = Wqkvt;   // alias: Wqkvt dead after QKV GEMM

  dim3 tb32x8(32, 8);

  rope_table_k<<<1024, 256, 0, stream>>>(cosT, sinT);
  cvt_f32_bf16<<<2048, 256, 0, stream>>>((const float4*)hs, (ushort4*)hsb, (Bc * Sc * Hc) / 4);
  // fused QKV weight: rows 0..4095 = Wq^T, 4096..6143 = Wk^T, 6144..8191 = Wv^T
  transpose_cvt<<<dim3(QD / 32, Hc / 32), tb32x8, 0, stream>>>(Wq, Wqkvt, Hc, QD);
  transpose_cvt<<<dim3(2048 / 32, Hc / 32), tb32x8, 0, stream>>>(Wk, Wqkvt + (size_t)4096 * Hc, Hc, 2048);
  transpose_cvt<<<dim3(2048 / 32, Hc / 32), tb32x8, 0, stream>>>(Wv, Wqkvt + (size_t)6144 * Hc, Hc, 2048);
  transpose_cvt<<<dim3(Hc / 32, QD / 32), tb32x8, 0, stream>>>(Wo, Wot, QD, Hc);

  // fused QKV projection: [4096][3584] x [8192][3584]^T -> [4096][8192]
  gemm256<u16><<<dim3(16 * 32), 512, 0, stream>>>(hsb, Wqkvt, QKVb, Bc * Sc, QS, Hc, 16);

  rope_apply<8><<<4096, 256, 0, stream>>>(QKVb + 4096, cosT, sinT);     // K (cols 4096..6143)
  transpose_v<<<dim3(Sc / 32, HDc / 32, Bc * NKV), tb32x8, 0, stream>>>(QKVb, Vtr);

  attn_fwd<<<dim3(16, NHc, Bc), 512, 0, stream>>>(QKVb, Vtr, cosT, sinT, AO);

  // output projection: [4096][4096] x [3584][4096]^T -> [4096][3584] fp32
  gemm256<float><<<dim3(16 * 14), 512, 0, stream>>>(AO, Wot, out, Bc * Sc, Hc, QD, 16);
}

// Round 15
// 591.606 us; speedup vs baseline: 1.4719x; 1.4719x over previous
//
#include <hip/hip_runtime.h>
#include <cstdint>
#include <cstddef>

// ---------------- types / helpers ----------------
typedef __bf16 bf16x8 __attribute__((ext_vector_type(8)));
typedef unsigned short u16x8 __attribute__((ext_vector_type(8)));
typedef float  f32x4  __attribute__((ext_vector_type(4)));
typedef unsigned short u16;

#define GLDS16(GP, LP) __builtin_amdgcn_global_load_lds( \
    (const __attribute__((address_space(1))) void*)(GP), \
    (__attribute__((address_space(3))) void*)(LP), 16, 0, 0)

__device__ __forceinline__ float b2f(u16 u) {
  unsigned int x = ((unsigned int)u) << 16;
  return __builtin_bit_cast(float, x);
}
__device__ __forceinline__ u16 f2b(float f) {  // RNE
  unsigned int u = __builtin_bit_cast(unsigned int, f);
  unsigned int r = (u + 0x7fffu + ((u >> 16) & 1u)) >> 16;
  return (u16)r;
}

// ---------------- problem constants ----------------
constexpr int Bc  = 2;
constexpr int Sc  = 2048;
constexpr int Hc  = 3584;
constexpr int NHc = 16;
constexpr int HDc = 256;
constexpr int NKV = 8;
constexpr int QD  = NHc * HDc;   // 4096
constexpr int QS  = 8192;        // fused QKV row stride (4096 Q + 2048 K + 2048 V)
constexpr float SCALE   = 0.0625f;   // 256^-0.5
constexpr float CAP     = 50.0f;
constexpr float INV_CAP = 1.0f / 50.0f;

// capped = CAP * tanh(raw*SCALE/CAP) = CAP - 2*CAP/(1 + exp(2*raw*SCALE/CAP))
// branch-free, graceful at +-inf, 1 transcendental.
__device__ __forceinline__ float softcap(float raw) {
  float e = __expf(raw * (2.0f * SCALE * INV_CAP));
  return CAP - (2.0f * CAP) * __builtin_amdgcn_rcpf(1.0f + e);
}

// ---------------- rope table ----------------
__global__ void rope_table_k(float* __restrict__ cosT, float* __restrict__ sinT) {
  int idx = blockIdx.x * 256 + threadIdx.x;      // 2048*128 total
  int s = idx >> 7, i = idx & 127;
  float inv = expf((float)i * -0.0719557841560639f);
  float ang = (float)s * inv;
  cosT[idx] = cosf(ang);
  sinT[idx] = sinf(ang);
}

// ---------------- fp32 -> bf16 elementwise (vectorized) ----------------
__global__ void cvt_f32_bf16(const float4* __restrict__ in, ushort4* __restrict__ out, int n4) {
  int i = blockIdx.x * 256 + threadIdx.x;
  int st = gridDim.x * 256;
  for (; i < n4; i += st) {
    float4 v = in[i];
    ushort4 u;
    u.x = f2b(v.x); u.y = f2b(v.y); u.z = f2b(v.z); u.w = f2b(v.w);
    out[i] = u;
  }
}

// ---------------- fp32 [R][C] -> bf16 [C][R] transpose-convert ----------------
__global__ void transpose_cvt(const float* __restrict__ in, u16* __restrict__ out, int R, int C) {
  __shared__ float t[32][33];
  int c0 = blockIdx.x * 32, r0 = blockIdx.y * 32;
  int tx = threadIdx.x, ty = threadIdx.y;   // (32,8)
#pragma unroll
  for (int i = 0; i < 4; i++)
    t[ty + i * 8][tx] = in[(size_t)(r0 + ty + i * 8) * C + c0 + tx];
  __syncthreads();
#pragma unroll
  for (int i = 0; i < 4; i++)
    out[(size_t)(c0 + ty + i * 8) * R + r0 + tx] = f2b(t[tx][ty + i * 8]);
}

// ---------------- bf16 per-head V transpose: QKV[.][6144+...] -> [B][NKV][256][S] ----------------
__global__ void transpose_v(const u16* __restrict__ QKV, u16* __restrict__ Vt) {
  __shared__ u16 t[32][33];
  int b = blockIdx.z >> 3, kvh = blockIdx.z & 7;
  int s0 = blockIdx.x * 32, d0 = blockIdx.y * 32;
  int tx = threadIdx.x, ty = threadIdx.y;
#pragma unroll
  for (int i = 0; i < 4; i++)
    t[ty + i * 8][tx] = QKV[(size_t)(b * Sc + s0 + ty + i * 8) * QS + 6144 + kvh * HDc + d0 + tx];
  __syncthreads();
#pragma unroll
  for (int i = 0; i < 4; i++)
    Vt[(size_t)((b * NKV + kvh) * HDc + d0 + ty + i * 8) * Sc + s0 + tx] = t[tx][ty + i * 8];
}

// ---------------- RoPE in-place on bf16, row stride QS (K only; Q fused in attn) ----------------
template <int NH>
__global__ void rope_apply(u16* __restrict__ X, const float* __restrict__ cosT,
                           const float* __restrict__ sinT) {
  constexpr int LS = (NH == 16) ? 4 : 3;
  int idx = blockIdx.x * 256 + threadIdx.x;
  const int i4 = (idx & 31) << 2;
  const int h = (idx >> 5) & (NH - 1);
  const int row = idx >> (5 + LS);
  const int s = row & (Sc - 1);
  u16* p = X + (size_t)row * QS + h * 256 + i4;
  ushort4 lo = *(const ushort4*)p;
  ushort4 hi = *(const ushort4*)(p + 128);
  float4 c = *(const float4*)(cosT + s * 128 + i4);
  float4 sn = *(const float4*)(sinT + s * 128 + i4);
  ushort4 nlo, nhi;
  { float xl = b2f(lo.x), xh = b2f(hi.x);
    nlo.x = f2b(xl * c.x - xh * sn.x); nhi.x = f2b(xh * c.x + xl * sn.x); }
  { float xl = b2f(lo.y), xh = b2f(hi.y);
    nlo.y = f2b(xl * c.y - xh * sn.y); nhi.y = f2b(xh * c.y + xl * sn.y); }
  { float xl = b2f(lo.z), xh = b2f(hi.z);
    nlo.z = f2b(xl * c.z - xh * sn.z); nhi.z = f2b(xh * c.z + xl * sn.z); }
  { float xl = b2f(lo.w), xh = b2f(hi.w);
    nlo.w = f2b(xl * c.w - xh * sn.w); nhi.w = f2b(xh * c.w + xl * sn.w); }
  *(ushort4*)p = nlo;
  *(ushort4*)(p + 128) = nhi;
}

// ---------------- GEMM 256x256 (Round-6 variant, best measured) ----------------
// 8 waves (2M x 4N), wave tile 128x64, BK=64, double-buffered LDS (128 KiB).
// All 24 ds_read_b128/K-tile issued fence-free up front; ONE sync point per K-tile.
// slot^(row&7) swizzle (0 conflicts), setprio (T5), XCD+GROUP_M=8 map (T1/L2).
template <typename OT>
__global__ __launch_bounds__(512, 1) void gemm256(const u16* __restrict__ A,
                                                  const u16* __restrict__ Bt,
                                                  OT* __restrict__ C,
                                                  int M, int N, int K, int GM) {
  __shared__ alignas(16) u16 As[2][256 * 64];   // 32 KiB each
  __shared__ alignas(16) u16 Bs[2][256 * 64];
  const int nwg = gridDim.x;
  const int cpx = nwg >> 3;                      // nwg % 8 == 0
  const int wgid = (blockIdx.x & 7) * cpx + (blockIdx.x >> 3);
  const int GN = nwg / GM;
  const int width = 8 * GN;
  const int grp = wgid / width;
  const int rem = wgid - grp * width;
  const int m0 = (grp * 8 + (rem & 7)) * 256;
  const int n0 = (rem >> 3) * 256;
  const int tid = threadIdx.x;
  const int lane = tid & 63;
  const int w = tid >> 6;
  const int wm = w >> 2, wn = w & 3;
  const int lg = lane >> 4, lr = lane & 15;
  const int nkt = K >> 6;

  auto STAGE = [&](int buf, int kt) {
    const int k0 = kt * 64;
#pragma unroll
    for (int i = 0; i < 4; i++) {
      int c = i * 512 + tid;
      int row = c >> 3, slot = c & 7;
      GLDS16(A + (size_t)(m0 + row) * K + k0 + (slot ^ (row & 7)) * 8,
             (char*)As[buf] + c * 16);
    }
#pragma unroll
    for (int i = 0; i < 4; i++) {
      int c = i * 512 + tid;
      int row = c >> 3, slot = c & 7;
      GLDS16(Bt + (size_t)(n0 + row) * K + k0 + (slot ^ (row & 7)) * 8,
             (char*)Bs[buf] + c * 16);
    }
  };

  f32x4 acc[8][4] = {};

  STAGE(0, 0);
  STAGE(1, 1);
  asm volatile("s_waitcnt vmcnt(8)" ::: "memory");   // tile 0 landed, tile 1 in flight
  __builtin_amdgcn_sched_barrier(0);
  __builtin_amdgcn_s_barrier();

  for (int kt = 0; kt < nkt; ++kt) {
    const int buf = kt & 1;
    bf16x8 bfr[4][2], af[4][2], af2[4][2];
#pragma unroll
    for (int j = 0; j < 4; j++)
#pragma unroll
      for (int ks = 0; ks < 2; ks++) {
        int row = wn * 64 + j * 16 + lr;
        bfr[j][ks] = *(const bf16x8*)&Bs[buf][row * 64 + ((ks * 4 + lg) ^ (row & 7)) * 8];
      }
#pragma unroll
    for (int i = 0; i < 4; i++)
#pragma unroll
      for (int ks = 0; ks < 2; ks++) {
        int row = wm * 128 + i * 16 + lr;
        af[i][ks] = *(const bf16x8*)&As[buf][row * 64 + ((ks * 4 + lg) ^ (row & 7)) * 8];
      }
#pragma unroll
    for (int i = 0; i < 4; i++)
#pragma unroll
      for (int ks = 0; ks < 2; ks++) {
        int row = wm * 128 + 64 + i * 16 + lr;
        af2[i][ks] = *(const bf16x8*)&As[buf][row * 64 + ((ks * 4 + lg) ^ (row & 7)) * 8];
      }
    __builtin_amdgcn_s_setprio(1);
#pragma unroll
    for (int i = 0; i < 4; i++)
#pragma unroll
      for (int j = 0; j < 4; j++)
#pragma unroll
        for (int ks = 0; ks < 2; ks++)
          acc[i][j] = __builtin_amdgcn_mfma_f32_16x16x32_bf16(
              af[i][ks], bfr[j][ks], acc[i][j], 0, 0, 0);
    __builtin_amdgcn_s_setprio(0);
    asm volatile("s_waitcnt vmcnt(0) lgkmcnt(0)" ::: "memory");
    __builtin_amdgcn_sched_barrier(0);
    __builtin_amdgcn_s_barrier();
    if (kt + 2 < nkt) STAGE(buf, kt + 2);
    __builtin_amdgcn_s_setprio(1);
#pragma unroll
    for (int i = 0; i < 4; i++)
#pragma unroll
      for (int j = 0; j < 4; j++)
#pragma unroll
        for (int ks = 0; ks < 2; ks++)
          acc[4 + i][j] = __builtin_amdgcn_mfma_f32_16x16x32_bf16(
              af2[i][ks], bfr[j][ks], acc[4 + i][j], 0, 0, 0);
    __builtin_amdgcn_s_setprio(0);
  }

#pragma unroll
  for (int i = 0; i < 8; i++) {
    const int row = m0 + wm * 128 + i * 16 + lg * 4;
#pragma unroll
    for (int j = 0; j < 4; j++) {
      const int col = n0 + wn * 64 + j * 16 + lr;
#pragma unroll
      for (int r = 0; r < 4; r++) {
        if constexpr (sizeof(OT) == 2)
          C[(size_t)(row + r) * N + col] = f2b(acc[i][j][r]);
        else
          C[(size_t)(row + r) * N + col] = acc[i][j][r];
      }
    }
  }
}

// ---------------- flash attention (R13 best-measured + T5 setprio on MFMA clusters) ----------------
// grid (16,16,2); qt = bz ? 15-bx : bx (balanced pairing). 8 waves x 16 q-rows.
// KV tile 64, DOUBLE-buffered K/V (128 KB) + Ps col-XOR (16 KB) = 144 KB.
// Counted vmcnt(8): next tile's 8 loads stay in flight across the barrier.
// Q-RoPE fused in prolog (pairs (d,d+128) are same-lane: qf[kk] <-> qf[kk+4]).
// T5: setprio(1) around QK^T and PV MFMA clusters (+4-7% attn, m191).
__global__ __launch_bounds__(512) void attn_fwd(const u16* __restrict__ QKV,
                                                const u16* __restrict__ Vt,
                                                const float* __restrict__ cosT,
                                                const float* __restrict__ sinT,
                                                u16* __restrict__ AO) {
  constexpr int KVB = 64;
  __shared__ alignas(16) u16 Ks[2][KVB * 256];   // [t][d], swizzled, 32 KB each
  __shared__ alignas(16) u16 Vs[2][256 * KVB];   // [d][t], swizzled, 32 KB each
  __shared__ alignas(16) u16 Ps[8][16][64];      // per-wave P, col ^= (q&7)<<3
  const int bx = blockIdx.x, h = blockIdx.y, b = blockIdx.z;
  const int qt = b ? (15 - bx) : bx;
  const int q0 = qt * 128;
  const int kvh = h >> 1;
  const int tid = threadIdx.x, w = tid >> 6, lane = tid & 63;
  const int lg = lane >> 4, lr = lane & 15;
  const int myrow = q0 + w * 16 + lr;            // this lane's Q row (A-operand row)

  // Q fragments + fused RoPE. qf[kk] covers d = kk*32 + lg*8 + e (kk<4 lo, kk>=4 hi).
  u16x8 qr[8];
  {
    const u16* qp = QKV + (size_t)(b * Sc + myrow) * QS + h * HDc + lg * 8;
#pragma unroll
    for (int kk = 0; kk < 8; kk++) qr[kk] = *(const u16x8*)(qp + kk * 32);
    const float* ct = cosT + myrow * 128 + lg * 8;
    const float* st = sinT + myrow * 128 + lg * 8;
#pragma unroll
    for (int kk = 0; kk < 4; kk++)
#pragma unroll
      for (int q4 = 0; q4 < 2; q4++) {
        float4 c = *(const float4*)(ct + kk * 32 + q4 * 4);
        float4 s = *(const float4*)(st + kk * 32 + q4 * 4);
#pragma unroll
        for (int e = 0; e < 4; e++) {
          int ei = q4 * 4 + e;
          float cc = (&c.x)[e], ss = (&s.x)[e];
          float lo = b2f(qr[kk][ei]), hi = b2f(qr[kk + 4][ei]);
          qr[kk][ei]     = f2b(lo * cc - hi * ss);
          qr[kk + 4][ei] = f2b(hi * cc + lo * ss);
        }
      }
  }
  bf16x8 qf[8];
#pragma unroll
  for (int kk = 0; kk < 8; kk++) qf[kk] = __builtin_bit_cast(bf16x8, qr[kk]);

  f32x4 o[16] = {};
  float m_r[4], l_r[4];
#pragma unroll
  for (int r = 0; r < 4; r++) { m_r[r] = -1e30f; l_r[r] = 0.0f; }
  const int my_qrow = q0 + w * 16 + lg * 4;
  const int wave_min_row = q0 + w * 16;
  const int wave_max_row = q0 + w * 16 + 15;

  const u16* kbase = QKV + (size_t)(b * Sc) * QS + 4096 + kvh * HDc;
  const u16* vbase = Vt + (size_t)((b * NKV + kvh) * HDc) * Sc;

  auto STAGE = [&](int buf, int t0) {
    // K tile [64][256]: 2048 16B-chunks, source pre-swizzled (slot ^ (row&7))
#pragma unroll
    for (int i = 0; i < 4; i++) {
      int c = i * 512 + tid;
      int row = c >> 5, slot = c & 31;
      GLDS16(kbase + (size_t)(t0 + row) * QS + (slot ^ (row & 7)) * 8,
             (char*)Ks[buf] + c * 16);
    }
    // V^T tile [256][64]: 2048 chunks, 8 slots/row, slot ^ (d&7)
#pragma unroll
    for (int i = 0; i < 4; i++) {
      int c = i * 512 + tid;
      int d = c >> 3, slot = c & 7;
      GLDS16(vbase + (size_t)d * Sc + t0 + (slot ^ (d & 7)) * 8,
             (char*)Vs[buf] + c * 16);
    }
  };

  const int nt = 2 * qt + 2;   // 64-wide tiles, t0 = 0 .. q0+64
  int cur = 0;
  STAGE(0, 0);
  for (int ti = 0; ti < nt; ++ti) {
    const int t0 = ti * 64;
    if (ti + 1 < nt) {
      STAGE(cur ^ 1, t0 + 64);
      asm volatile("s_waitcnt vmcnt(8)" ::: "memory");   // tile-ti landed; next in flight
    } else {
      asm volatile("s_waitcnt vmcnt(0)" ::: "memory");
    }
    __builtin_amdgcn_sched_barrier(0);
    __builtin_amdgcn_s_barrier();

    if (t0 <= wave_max_row) {   // wave-uniform: skip fully-masked tiles
      const u16* KsT = Ks[cur];
      const u16* VsT = Vs[cur];

      // scores: 4 t-frags x 8 k-steps (swizzled reads)
      f32x4 sc[4];
      __builtin_amdgcn_s_setprio(1);
#pragma unroll
      for (int j = 0; j < 4; j++) {
        f32x4 a = {0.f, 0.f, 0.f, 0.f};
        const int row = j * 16 + lr;
#pragma unroll
        for (int kk = 0; kk < 8; kk++) {
          int s0 = (kk * 4 + lg) ^ (lr & 7);
          bf16x8 kf = *(const bf16x8*)&KsT[row * 256 + s0 * 8];
          a = __builtin_amdgcn_mfma_f32_16x16x32_bf16(qf[kk], kf, a, 0, 0, 0);
        }
        sc[j] = a;
      }
      __builtin_amdgcn_s_setprio(0);

      float tmax[4] = {-1e30f, -1e30f, -1e30f, -1e30f};
      if (t0 + 63 > wave_min_row) {  // tile touches diagonal for this wave
#pragma unroll
        for (int j = 0; j < 4; j++)
#pragma unroll
          for (int r = 0; r < 4; r++) {
            float x = softcap(sc[j][r]);
            if (t0 + j * 16 + lr > my_qrow + r) x = -1e9f;
            sc[j][r] = x;
            tmax[r] = fmaxf(tmax[r], x);
          }
      } else {
#pragma unroll
        for (int j = 0; j < 4; j++)
#pragma unroll
          for (int r = 0; r < 4; r++) {
            float x = softcap(sc[j][r]);
            sc[j][r] = x;
            tmax[r] = fmaxf(tmax[r], x);
          }
      }
#pragma unroll
      for (int xm = 1; xm < 16; xm <<= 1)
#pragma unroll
        for (int r = 0; r < 4; r++) tmax[r] = fmaxf(tmax[r], __shfl_xor(tmax[r], xm, 64));

      // T13 defer-max
      bool need = false;
#pragma unroll
      for (int r = 0; r < 4; r++) need |= (tmax[r] > m_r[r] + 8.0f);
      if (__any(need)) {
        float scal[4];
#pragma unroll
        for (int r = 0; r < 4; r++) {
          float mn = fmaxf(m_r[r], tmax[r]);
          scal[r] = __expf(m_r[r] - mn);
          m_r[r] = mn;
          l_r[r] *= scal[r];
        }
#pragma unroll
        for (int df = 0; df < 16; df++)
#pragma unroll
          for (int r = 0; r < 4; r++) o[df][r] *= scal[r];
      }

      float psum[4] = {0.f, 0.f, 0.f, 0.f};
#pragma unroll
      for (int j = 0; j < 4; j++)
#pragma unroll
        for (int r = 0; r < 4; r++) {
          float p = __expf(sc[j][r] - m_r[r]);
          psum[r] += p;
          // col-XOR swizzle: element (q, t) stored at col t ^ ((q&7)<<3)
          int q = lg * 4 + r;
          Ps[w][q][(j * 16 + lr) ^ ((q & 7) << 3)] = f2b(p);
        }
#pragma unroll
      for (int xm = 1; xm < 16; xm <<= 1)
#pragma unroll
        for (int r = 0; r < 4; r++) psum[r] += __shfl_xor(psum[r], xm, 64);
#pragma unroll
      for (int r = 0; r < 4; r++) l_r[r] += psum[r];

      // PV: A = P rows (q=lr), B = V^T rows (d), 2 k-steps over t.
      // Read swizzle: t-chunk g at row lr lives at col ((g ^ (lr&7)) * 8).
      bf16x8 pf0 = *(const bf16x8*)&Ps[w][lr][(lg ^ (lr & 7)) * 8];
      bf16x8 pf1 = *(const bf16x8*)&Ps[w][lr][((lg ^ 4) ^ (lr & 7)) * 8];
      __builtin_amdgcn_s_setprio(1);
#pragma unroll
      for (int df = 0; df < 16; df++) {
        const int d = df * 16 + lr;
        int s0 = lg ^ (d & 7);
        int s1 = (4 + lg) ^ (d & 7);
        bf16x8 vf0 = *(const bf16x8*)&VsT[d * KVB + s0 * 8];
        o[df] = __builtin_amdgcn_mfma_f32_16x16x32_bf16(pf0, vf0, o[df], 0, 0, 0);
        bf16x8 vf1 = *(const bf16x8*)&VsT[d * KVB + s1 * 8];
        o[df] = __builtin_amdgcn_mfma_f32_16x16x32_bf16(pf1, vf1, o[df], 0, 0, 0);
      }
      __builtin_amdgcn_s_setprio(0);
    }

    __builtin_amdgcn_s_barrier();
    cur ^= 1;
  }

  float inv_l[4];
#pragma unroll
  for (int r = 0; r < 4; r++) inv_l[r] = 1.0f / l_r[r];
  u16* op = AO + (size_t)(b * Sc + my_qrow) * QD + h * HDc + lr;
#pragma unroll
  for (int df = 0; df < 16; df++)
#pragma unroll
    for (int r = 0; r < 4; r++)
      op[(size_t)r * QD + df * 16] = f2b(o[df][r] * inv_l[r]);
}

// ---------------- host launcher ----------------
extern "C" void kernel_launch(void* const* d_in, const int* in_sizes, int n_in,
                              void* d_out, int out_size, void* d_ws, size_t ws_size,
                              hipStream_t stream) {
  (void)in_sizes; (void)n_in; (void)out_size; (void)ws_size;
  const float* hs = (const float*)d_in[0];
  // d_in[1] = attention_mask (causal; applied analytically)
  const float* Wq = (const float*)d_in[2];
  const float* Wk = (const float*)d_in[3];
  const float* Wv = (const float*)d_in[4];
  const float* Wo = (const float*)d_in[5];
  float* out = (float*)d_out;
  char* ws = (char*)d_ws;

  float* cosT = (float*)(ws + 0);                 // 1 MB
  float* sinT = (float*)(ws + 1048576);           // 1 MB
  u16* hsb    = (u16*)(ws + 2097152);             // [4096][3584]
  u16* Wqkvt  = (u16*)(ws + 31457280);            // [8192][3584]
  u16* Wot    = (u16*)(ws + 90177536);            // [3584][4096]
  u16* QKVb   = (u16*)(ws + 119537664);           // [4096][8192]
  u16* Vtr    = hsb;     // alias: hsb dead after QKV GEMM
  u16* AO     = Wqkvt;   // alias: Wqkvt dead after QKV GEMM

  dim3 tb32x8(32, 8);

  rope_table_k<<<1024, 256, 0, stream>>>(cosT, sinT);
  cvt_f32_bf16<<<2048, 256, 0, stream>>>((const float4*)hs, (ushort4*)hsb, (Bc * Sc * Hc) / 4);
  // fused QKV weight: rows 0..4095 = Wq^T, 4096..6143 = Wk^T, 6144..8191 = Wv^T
  transpose_cvt<<<dim3(QD / 32, Hc / 32), tb32x8, 0, stream>>>(Wq, Wqkvt, Hc, QD);
  transpose_cvt<<<dim3(2048 / 32, Hc / 32), tb32x8, 0, stream>>>(Wk, Wqkvt + (size_t)4096 * Hc, Hc, 2048);
  transpose_cvt<<<dim3(2048 / 32, Hc / 32), tb32x8, 0, stream>>>(Wv, Wqkvt + (size_t)6144 * Hc, Hc, 2048);
  transpose_cvt<<<dim3(Hc / 32, QD / 32), tb32x8, 0, stream>>>(Wo, Wot, QD, Hc);

  // fused QKV projection: [4096][3584] x [8192][3584]^T -> [4096][8192]
  gemm256<u16><<<dim3(16 * 32), 512, 0, stream>>>(hsb, Wqkvt, QKVb, Bc * Sc, QS, Hc, 16);

  rope_apply<8><<<4096, 256, 0, stream>>>(QKVb + 4096, cosT, sinT);     // K (cols 4096..6143)
  transpose_v<<<dim3(Sc / 32, HDc / 32, Bc * NKV), tb32x8, 0, stream>>>(QKVb, Vtr);

  attn_fwd<<<dim3(16, NHc, Bc), 512, 0, stream>>>(QKVb, Vtr, cosT, sinT, AO);

  // output projection: [4096][4096] x [3584][4096]^T -> [4096][3584] fp32
  gemm256<float><<<dim3(16 * 14), 512, 0, stream>>>(AO, Wot, out, Bc * Sc, Hc, QD, 16);
}